// Round 1
// baseline (161.555 us; speedup 1.0000x reference)
//
#include <hip/hip_runtime.h>
#include <hip/hip_bf16.h>

typedef __bf16 bf16x8 __attribute__((ext_vector_type(8)));
typedef float  f32x4  __attribute__((ext_vector_type(4)));

// async 16B global -> LDS (wave-uniform LDS base + lane*16)
__device__ __forceinline__ void gload_lds16(const void* g, void* l) {
  __builtin_amdgcn_global_load_lds(
      (const __attribute__((address_space(1))) unsigned int*)g,
      (__attribute__((address_space(3))) unsigned int*)l, 16, 0, 0);
}

// ---------------- fp32 -> bf16 convert (vectorized) ----------------
__global__ void k_cvt(const float* __restrict__ s, __bf16* __restrict__ d, int n4) {
  int i = blockIdx.x * blockDim.x + threadIdx.x;
  if (i >= n4) return;
  float4 v = ((const float4*)s)[i];
  union { __bf16 h[4]; uint2 u; } o;
  o.h[0] = (__bf16)v.x; o.h[1] = (__bf16)v.y;
  o.h[2] = (__bf16)v.z; o.h[3] = (__bf16)v.w;
  ((uint2*)d)[i] = o.u;
}

// ---------------- C[M,N] = A[M,K] @ B[N,K]^T + bias ----------------
// 128x128 tile, BK=32, 256 threads (4 waves in 2x2), 16x16x32 bf16 MFMA.
template<bool OUT_BF16>
__global__ __launch_bounds__(256, 2)
void k_gemm_bt(const __bf16* __restrict__ A, const __bf16* __restrict__ B,
               const float* __restrict__ bias, void* __restrict__ C,
               int M, int N, int K) {
  __shared__ __bf16 At[128 * 32];
  __shared__ __bf16 Bt[128 * 32];
  const int tid  = threadIdx.x;
  const int lane = tid & 63;
  const int w    = tid >> 6;
  const int wr   = w >> 1, wc = w & 1;
  const int bm   = blockIdx.y * 128, bn = blockIdx.x * 128;

  f32x4 acc[4][4] = {};

  // staging: per 16B-load instruction, thread t covers row (t>>2), col (t&3)*8
  const __bf16* ga = A + (size_t)(bm + (tid >> 2)) * K + (tid & 3) * 8;
  const __bf16* gb = B + (size_t)(bn + (tid >> 2)) * K + (tid & 3) * 8;

  for (int k0 = 0; k0 < K; k0 += 32) {
    __syncthreads();  // previous iteration's LDS reads complete
    gload_lds16(ga + k0,                  &At[(w * 16) * 32]);
    gload_lds16(ga + k0 + (size_t)64 * K, &At[(64 + w * 16) * 32]);
    gload_lds16(gb + k0,                  &Bt[(w * 16) * 32]);
    gload_lds16(gb + k0 + (size_t)64 * K, &Bt[(64 + w * 16) * 32]);
    __syncthreads();  // drain vmcnt: tiles visible

    bf16x8 a[4], b[4];
#pragma unroll
    for (int mt = 0; mt < 4; ++mt)
      a[mt] = *(const bf16x8*)&At[(wr * 64 + mt * 16 + (lane & 15)) * 32 + (lane >> 4) * 8];
#pragma unroll
    for (int nt = 0; nt < 4; ++nt)
      b[nt] = *(const bf16x8*)&Bt[(wc * 64 + nt * 16 + (lane & 15)) * 32 + (lane >> 4) * 8];
#pragma unroll
    for (int mt = 0; mt < 4; ++mt)
#pragma unroll
      for (int nt = 0; nt < 4; ++nt)
        acc[mt][nt] = __builtin_amdgcn_mfma_f32_16x16x32_bf16(a[mt], b[nt], acc[mt][nt], 0, 0, 0);
  }

#pragma unroll
  for (int nt = 0; nt < 4; ++nt) {
    const int col = bn + wc * 64 + nt * 16 + (lane & 15);
    const float bv = bias[col];
#pragma unroll
    for (int mt = 0; mt < 4; ++mt) {
#pragma unroll
      for (int r = 0; r < 4; ++r) {
        const int row = bm + wr * 64 + mt * 16 + (lane >> 4) * 4 + r;
        const float v = acc[mt][nt][r] + bv;
        if (OUT_BF16) ((__bf16*)C)[(size_t)row * N + col] = (__bf16)v;
        else          ((float*)C)[(size_t)row * N + col]  = v;
      }
    }
  }
}

// ---------------- flash attention (Q = K = V = qbuf head slices) ----------------
// grid: x = S/128 (16), y = B*H (32). 4 waves x 32 q-rows. KV-tile = 64.
// Swapped QK^T: S^T = mfma(A=K, B=Q) -> kv-reduction needs only shfl_xor 16,32.
// XOR swizzle on 128B-row LDS tiles: elem_idx = row*64 + (col ^ ((row&7)<<3)).
#define SWZ(row, col) ((row) * 64 + ((col) ^ (((row) & 7) << 3)))

__global__ __launch_bounds__(256, 2)
void k_attn(const __bf16* __restrict__ q, __bf16* __restrict__ o) {
  __shared__ __bf16 Kt[64 * 64];
  __shared__ __bf16 Vt[64 * 64];         // transposed: Vt[d][kv]
  __shared__ __bf16 Pt[4][32 * 64];      // per-wave P[q][kv]
  const int tid = threadIdx.x, lane = tid & 63, w = tid >> 6;
  const int bh = blockIdx.y;
  const int b = bh >> 4, h = bh & 15;
  const size_t base = ((size_t)b * 2048) * 1024 + h * 64;  // [b, s, h*64+d]
  const int q0 = blockIdx.x * 128 + w * 32;

  // Q fragments in registers (B-operand role): qb[qf][ks]
  bf16x8 qb[2][2];
#pragma unroll
  for (int qf = 0; qf < 2; ++qf)
#pragma unroll
    for (int ks = 0; ks < 2; ++ks)
      qb[qf][ks] = *(const bf16x8*)&q[base + (size_t)(q0 + qf * 16 + (lane & 15)) * 1024
                                      + ks * 32 + (lane >> 4) * 8];

  f32x4 O[2][4] = {};
  float m_run[2] = {-1e30f, -1e30f};
  float l_run[2] = {0.f, 0.f};

  const int r0 = tid >> 3, c0 = (tid & 7) * 8;  // staging coords

  for (int kt = 0; kt < 2048; kt += 64) {
    // load KV tile (registers first; LDS dest is swizzled so no global_load_lds)
    bf16x8 v0 = *(const bf16x8*)&q[base + (size_t)(kt + r0) * 1024 + c0];
    bf16x8 v1 = *(const bf16x8*)&q[base + (size_t)(kt + 32 + r0) * 1024 + c0];
    __syncthreads();  // previous tile's reads complete
    *(bf16x8*)&Kt[SWZ(r0, c0)]      = v0;
    *(bf16x8*)&Kt[SWZ(r0 + 32, c0)] = v1;
#pragma unroll
    for (int j = 0; j < 8; ++j) {
      Vt[SWZ(c0 + j, r0)]      = v0[j];
      Vt[SWZ(c0 + j, r0 + 32)] = v1[j];
    }
    __syncthreads();

    // S^T[kv, q] = K · Q^T
    f32x4 s[4][2] = {};
#pragma unroll
    for (int ks = 0; ks < 2; ++ks) {
#pragma unroll
      for (int kvf = 0; kvf < 4; ++kvf) {
        bf16x8 ka = *(const bf16x8*)&Kt[SWZ(kvf * 16 + (lane & 15), ks * 32 + (lane >> 4) * 8)];
#pragma unroll
        for (int qf = 0; qf < 2; ++qf)
          s[kvf][qf] = __builtin_amdgcn_mfma_f32_16x16x32_bf16(ka, qb[qf][ks], s[kvf][qf], 0, 0, 0);
      }
    }

    // online softmax; per lane: q-col = (lane&15)+16*qf, kv rows in regs
#pragma unroll
    for (int qf = 0; qf < 2; ++qf) {
      float mx = -1e30f;
#pragma unroll
      for (int kvf = 0; kvf < 4; ++kvf)
#pragma unroll
        for (int r = 0; r < 4; ++r)
          mx = fmaxf(mx, s[kvf][qf][r]);
      mx = fmaxf(mx, __shfl_xor(mx, 16));
      mx = fmaxf(mx, __shfl_xor(mx, 32));
      mx *= 0.125f;
      const float m_new = fmaxf(m_run[qf], mx);
      const float ps = __expf(m_run[qf] - m_new);
      float lsum = 0.f;
#pragma unroll
      for (int kvf = 0; kvf < 4; ++kvf)
#pragma unroll
        for (int r = 0; r < 4; ++r) {
          const float p = __expf(0.125f * s[kvf][qf][r] - m_new);
          s[kvf][qf][r] = p;
          lsum += p;
        }
      lsum += __shfl_xor(lsum, 16);
      lsum += __shfl_xor(lsum, 32);
      l_run[qf] = l_run[qf] * ps + lsum;
      m_run[qf] = m_new;
      // rescale O (row layout: row%16 = (lane>>4)*4 + r)
#pragma unroll
      for (int r = 0; r < 4; ++r) {
        const float rs = __shfl(ps, (lane >> 4) * 4 + r);
#pragma unroll
        for (int nf = 0; nf < 4; ++nf)
          O[qf][nf][r] *= rs;
      }
      // write P^T -> P[q][kv] in LDS (4 consecutive kv per lane -> one b64)
#pragma unroll
      for (int kvf = 0; kvf < 4; ++kvf) {
        union { __bf16 h[4]; uint2 u; } pk;
        pk.h[0] = (__bf16)s[kvf][qf][0]; pk.h[1] = (__bf16)s[kvf][qf][1];
        pk.h[2] = (__bf16)s[kvf][qf][2]; pk.h[3] = (__bf16)s[kvf][qf][3];
        *(uint2*)&Pt[w][SWZ(qf * 16 + (lane & 15), kvf * 16 + (lane >> 4) * 4)] = pk.u;
      }
    }

    // PV: O[q, d] += P[q, kv] * V[kv, d]
#pragma unroll
    for (int ks = 0; ks < 2; ++ks) {
      bf16x8 pa[2];
#pragma unroll
      for (int qf = 0; qf < 2; ++qf)
        pa[qf] = *(const bf16x8*)&Pt[w][SWZ(qf * 16 + (lane & 15), ks * 32 + (lane >> 4) * 8)];
#pragma unroll
      for (int nf = 0; nf < 4; ++nf) {
        bf16x8 vb = *(const bf16x8*)&Vt[SWZ(nf * 16 + (lane & 15), ks * 32 + (lane >> 4) * 8)];
#pragma unroll
        for (int qf = 0; qf < 2; ++qf)
          O[qf][nf] = __builtin_amdgcn_mfma_f32_16x16x32_bf16(pa[qf], vb, O[qf][nf], 0, 0, 0);
      }
    }
  }

  // epilogue: divide by l, store bf16
#pragma unroll
  for (int qf = 0; qf < 2; ++qf) {
    float inv[4];
#pragma unroll
    for (int r = 0; r < 4; ++r)
      inv[r] = 1.0f / __shfl(l_run[qf], (lane >> 4) * 4 + r);
#pragma unroll
    for (int nf = 0; nf < 4; ++nf) {
#pragma unroll
      for (int r = 0; r < 4; ++r) {
        const int row = q0 + qf * 16 + (lane >> 4) * 4 + r;
        const int col = nf * 16 + (lane & 15);
        o[base + (size_t)row * 1024 + col] = (__bf16)(O[qf][nf][r] * inv[r]);
      }
    }
  }
}

// ---------------- launch ----------------
extern "C" void kernel_launch(void* const* d_in, const int* in_sizes, int n_in,
                              void* d_out, int out_size, void* d_ws, size_t ws_size,
                              hipStream_t stream) {
  const float* x  = (const float*)d_in[0];
  const float* Wq = (const float*)d_in[1];
  const float* bq = (const float*)d_in[2];
  const float* Wo = (const float*)d_in[3];
  const float* bo = (const float*)d_in[4];

  char* ws = (char*)d_ws;
  __bf16* xb  = (__bf16*)(ws);                          // 8 MB  [4096,1024]
  __bf16* wqb = (__bf16*)(ws + ((size_t)8  << 20));     // 2 MB  [1024,1024]
  __bf16* wob = (__bf16*)(ws + ((size_t)10 << 20));     // 2 MB
  __bf16* qb  = (__bf16*)(ws + ((size_t)12 << 20));     // 8 MB  q projection
  __bf16* ab  = (__bf16*)(ws + ((size_t)20 << 20));     // 8 MB  attn output

  const int M = 4096, N = 1024, K = 1024;

  k_cvt<<<(M * K / 4 + 255) / 256, 256, 0, stream>>>(x,  xb,  M * K / 4);
  k_cvt<<<(N * K / 4 + 255) / 256, 256, 0, stream>>>(Wq, wqb, N * K / 4);
  k_cvt<<<(N * K / 4 + 255) / 256, 256, 0, stream>>>(Wo, wob, N * K / 4);

  k_gemm_bt<true ><<<dim3(8, 32), 256, 0, stream>>>(xb, wqb, bq, qb,    M, N, K);
  k_attn          <<<dim3(16, 32), 256, 0, stream>>>(qb, ab);
  k_gemm_bt<false><<<dim3(8, 32), 256, 0, stream>>>(ab, wob, bo, d_out, M, N, K);
}

// Round 5
// 135.370 us; speedup vs baseline: 1.1934x; 1.1934x over previous
//
#include <hip/hip_runtime.h>
#include <hip/hip_bf16.h>

typedef __bf16 bf16x8 __attribute__((ext_vector_type(8)));
typedef float  f32x4  __attribute__((ext_vector_type(4)));

// async 16B global -> LDS (wave-uniform LDS base + lane*16)
__device__ __forceinline__ void gload_lds16(const void* g, void* l) {
  __builtin_amdgcn_global_load_lds(
      (const __attribute__((address_space(1))) unsigned int*)g,
      (__attribute__((address_space(3))) unsigned int*)l, 16, 0, 0);
}

// ---------------- fp32 -> bf16 convert (vectorized) ----------------
__global__ void k_cvt(const float* __restrict__ s, __bf16* __restrict__ d, int n4) {
  int i = blockIdx.x * blockDim.x + threadIdx.x;
  if (i >= n4) return;
  float4 v = ((const float4*)s)[i];
  union { __bf16 h[4]; uint2 u; } o;
  o.h[0] = (__bf16)v.x; o.h[1] = (__bf16)v.y;
  o.h[2] = (__bf16)v.z; o.h[3] = (__bf16)v.w;
  ((uint2*)d)[i] = o.u;
}

// ---------------- C[M,N] = A[M,K] @ B[N,K]^T + bias ----------------
// 128x128 tile, BK=32, 256 threads (4 waves in 2x2), 16x16x32 bf16 MFMA.
// (round-1 proven version, verbatim)
template<bool OUT_BF16>
__global__ __launch_bounds__(256, 2)
void k_gemm_bt(const __bf16* __restrict__ A, const __bf16* __restrict__ B,
               const float* __restrict__ bias, void* __restrict__ C,
               int M, int N, int K) {
  __shared__ __bf16 At[128 * 32];
  __shared__ __bf16 Bt[128 * 32];
  const int tid  = threadIdx.x;
  const int lane = tid & 63;
  const int w    = tid >> 6;
  const int wr   = w >> 1, wc = w & 1;
  const int bm   = blockIdx.y * 128, bn = blockIdx.x * 128;

  f32x4 acc[4][4] = {};

  const __bf16* ga = A + (size_t)(bm + (tid >> 2)) * K + (tid & 3) * 8;
  const __bf16* gb = B + (size_t)(bn + (tid >> 2)) * K + (tid & 3) * 8;

  for (int k0 = 0; k0 < K; k0 += 32) {
    __syncthreads();
    gload_lds16(ga + k0,                  &At[(w * 16) * 32]);
    gload_lds16(ga + k0 + (size_t)64 * K, &At[(64 + w * 16) * 32]);
    gload_lds16(gb + k0,                  &Bt[(w * 16) * 32]);
    gload_lds16(gb + k0 + (size_t)64 * K, &Bt[(64 + w * 16) * 32]);
    __syncthreads();

    bf16x8 a[4], b[4];
#pragma unroll
    for (int mt = 0; mt < 4; ++mt)
      a[mt] = *(const bf16x8*)&At[(wr * 64 + mt * 16 + (lane & 15)) * 32 + (lane >> 4) * 8];
#pragma unroll
    for (int nt = 0; nt < 4; ++nt)
      b[nt] = *(const bf16x8*)&Bt[(wc * 64 + nt * 16 + (lane & 15)) * 32 + (lane >> 4) * 8];
#pragma unroll
    for (int mt = 0; mt < 4; ++mt)
#pragma unroll
      for (int nt = 0; nt < 4; ++nt)
        acc[mt][nt] = __builtin_amdgcn_mfma_f32_16x16x32_bf16(a[mt], b[nt], acc[mt][nt], 0, 0, 0);
  }

#pragma unroll
  for (int nt = 0; nt < 4; ++nt) {
    const int col = bn + wc * 64 + nt * 16 + (lane & 15);
    const float bv = bias[col];
#pragma unroll
    for (int mt = 0; mt < 4; ++mt) {
#pragma unroll
      for (int r = 0; r < 4; ++r) {
        const int row = bm + wr * 64 + mt * 16 + (lane >> 4) * 4 + r;
        const float v = acc[mt][nt][r] + bv;
        if (OUT_BF16) ((__bf16*)C)[(size_t)row * N + col] = (__bf16)v;
        else          ((float*)C)[(size_t)row * N + col]  = v;
      }
    }
  }
}

// ---------------- flash attention (Q = K = V = qbuf head slices) ----------------
// round-1 proven skeleton. Changes vs round 1:
//  (1) Vt swizzle row&56 (was (row&7)<<3): per-write-instruction rows {j,j+8,..,j+56}
//      now get 8 distinct XORs -> transpose writes spread over all 32 banks (was 8-way).
//  (2) next-tile KV prefetch into registers, issued before compute.
#define SWZ(row, col)  ((row) * 64 + ((col) ^ (((row) & 7) << 3)))
#define SWZV(row, col) ((row) * 64 + ((col) ^ ((row) & 56)))

__global__ __launch_bounds__(256, 2)
void k_attn(const __bf16* __restrict__ q, __bf16* __restrict__ o) {
  __shared__ __bf16 Kt[64 * 64];
  __shared__ __bf16 Vt[64 * 64];         // transposed: Vt[d][kv], SWZV swizzle
  __shared__ __bf16 Pt[4][32 * 64];      // per-wave P[q][kv]
  const int tid = threadIdx.x, lane = tid & 63, w = tid >> 6;
  const int bh = blockIdx.y;
  const int b = bh >> 4, h = bh & 15;
  const size_t base = ((size_t)b * 2048) * 1024 + h * 64;  // [b, s, h*64+d]
  const int q0 = blockIdx.x * 128 + w * 32;

  // Q fragments in registers (B-operand role): qb[qf][ks]
  bf16x8 qb[2][2];
#pragma unroll
  for (int qf = 0; qf < 2; ++qf)
#pragma unroll
    for (int ks = 0; ks < 2; ++ks)
      qb[qf][ks] = *(const bf16x8*)&q[base + (size_t)(q0 + qf * 16 + (lane & 15)) * 1024
                                      + ks * 32 + (lane >> 4) * 8];

  f32x4 O[2][4] = {};
  float m_run[2] = {-1e30f, -1e30f};
  float l_run[2] = {0.f, 0.f};

  const int r0 = tid >> 3, c0 = (tid & 7) * 8;  // staging coords

  // prologue: tile 0 into registers
  bf16x8 v0 = *(const bf16x8*)&q[base + (size_t)(r0) * 1024 + c0];
  bf16x8 v1 = *(const bf16x8*)&q[base + (size_t)(32 + r0) * 1024 + c0];

  for (int kt = 0; kt < 2048; kt += 64) {
    __syncthreads();  // previous tile's LDS reads complete
    *(bf16x8*)&Kt[SWZ(r0, c0)]      = v0;
    *(bf16x8*)&Kt[SWZ(r0 + 32, c0)] = v1;
#pragma unroll
    for (int j = 0; j < 8; ++j) {
      Vt[SWZV(c0 + j, r0)]      = v0[j];
      Vt[SWZV(c0 + j, r0 + 32)] = v1[j];
    }
    __syncthreads();

    // prefetch next tile into registers; consumed at next iteration's writes
    if (kt < 2048 - 64) {
      v0 = *(const bf16x8*)&q[base + (size_t)(kt + 64 + r0) * 1024 + c0];
      v1 = *(const bf16x8*)&q[base + (size_t)(kt + 96 + r0) * 1024 + c0];
    }

    // S^T[kv, q] = K · Q^T
    f32x4 s[4][2] = {};
#pragma unroll
    for (int ks = 0; ks < 2; ++ks) {
#pragma unroll
      for (int kvf = 0; kvf < 4; ++kvf) {
        bf16x8 ka = *(const bf16x8*)&Kt[SWZ(kvf * 16 + (lane & 15), ks * 32 + (lane >> 4) * 8)];
#pragma unroll
        for (int qf = 0; qf < 2; ++qf)
          s[kvf][qf] = __builtin_amdgcn_mfma_f32_16x16x32_bf16(ka, qb[qf][ks], s[kvf][qf], 0, 0, 0);
      }
    }

    // online softmax; per lane: q-col = (lane&15)+16*qf, kv rows in regs
#pragma unroll
    for (int qf = 0; qf < 2; ++qf) {
      float mx = -1e30f;
#pragma unroll
      for (int kvf = 0; kvf < 4; ++kvf)
#pragma unroll
        for (int r = 0; r < 4; ++r)
          mx = fmaxf(mx, s[kvf][qf][r]);
      mx = fmaxf(mx, __shfl_xor(mx, 16));
      mx = fmaxf(mx, __shfl_xor(mx, 32));
      mx *= 0.125f;
      const float m_new = fmaxf(m_run[qf], mx);
      const float ps = __expf(m_run[qf] - m_new);
      float lsum = 0.f;
#pragma unroll
      for (int kvf = 0; kvf < 4; ++kvf)
#pragma unroll
        for (int r = 0; r < 4; ++r) {
          const float p = __expf(0.125f * s[kvf][qf][r] - m_new);
          s[kvf][qf][r] = p;
          lsum += p;
        }
      lsum += __shfl_xor(lsum, 16);
      lsum += __shfl_xor(lsum, 32);
      l_run[qf] = l_run[qf] * ps + lsum;
      m_run[qf] = m_new;
      // rescale O (row layout: row%16 = (lane>>4)*4 + r)
#pragma unroll
      for (int r = 0; r < 4; ++r) {
        const float rs = __shfl(ps, (lane >> 4) * 4 + r);
#pragma unroll
        for (int nf = 0; nf < 4; ++nf)
          O[qf][nf][r] *= rs;
      }
      // write P^T -> P[q][kv] in LDS (4 consecutive kv per lane -> one b64)
#pragma unroll
      for (int kvf = 0; kvf < 4; ++kvf) {
        union { __bf16 h[4]; uint2 u; } pk;
        pk.h[0] = (__bf16)s[kvf][qf][0]; pk.h[1] = (__bf16)s[kvf][qf][1];
        pk.h[2] = (__bf16)s[kvf][qf][2]; pk.h[3] = (__bf16)s[kvf][qf][3];
        *(uint2*)&Pt[w][SWZ(qf * 16 + (lane & 15), kvf * 16 + (lane >> 4) * 4)] = pk.u;
      }
    }

    // PV: O[q, d] += P[q, kv] * V[kv, d]
#pragma unroll
    for (int ks = 0; ks < 2; ++ks) {
      bf16x8 pa[2];
#pragma unroll
      for (int qf = 0; qf < 2; ++qf)
        pa[qf] = *(const bf16x8*)&Pt[w][SWZ(qf * 16 + (lane & 15), ks * 32 + (lane >> 4) * 8)];
#pragma unroll
      for (int nf = 0; nf < 4; ++nf) {
        bf16x8 vb = *(const bf16x8*)&Vt[SWZV(nf * 16 + (lane & 15), ks * 32 + (lane >> 4) * 8)];
#pragma unroll
        for (int qf = 0; qf < 2; ++qf)
          O[qf][nf] = __builtin_amdgcn_mfma_f32_16x16x32_bf16(pa[qf], vb, O[qf][nf], 0, 0, 0);
      }
    }
  }

  // epilogue: divide by l, store bf16
#pragma unroll
  for (int qf = 0; qf < 2; ++qf) {
    float inv[4];
#pragma unroll
    for (int r = 0; r < 4; ++r)
      inv[r] = 1.0f / __shfl(l_run[qf], (lane >> 4) * 4 + r);
#pragma unroll
    for (int nf = 0; nf < 4; ++nf) {
#pragma unroll
      for (int r = 0; r < 4; ++r) {
        const int row = q0 + qf * 16 + (lane >> 4) * 4 + r;
        const int col = nf * 16 + (lane & 15);
        o[base + (size_t)row * 1024 + col] = (__bf16)(O[qf][nf][r] * inv[r]);
      }
    }
  }
}

// ---------------- launch ----------------
extern "C" void kernel_launch(void* const* d_in, const int* in_sizes, int n_in,
                              void* d_out, int out_size, void* d_ws, size_t ws_size,
                              hipStream_t stream) {
  const float* x  = (const float*)d_in[0];
  const float* Wq = (const float*)d_in[1];
  const float* bq = (const float*)d_in[2];
  const float* Wo = (const float*)d_in[3];
  const float* bo = (const float*)d_in[4];

  char* ws = (char*)d_ws;
  __bf16* xb  = (__bf16*)(ws);                          // 8 MB  [4096,1024]
  __bf16* wqb = (__bf16*)(ws + ((size_t)8  << 20));     // 2 MB  [1024,1024]
  __bf16* wob = (__bf16*)(ws + ((size_t)10 << 20));     // 2 MB
  __bf16* qb  = (__bf16*)(ws + ((size_t)12 << 20));     // 8 MB  q projection
  __bf16* ab  = (__bf16*)(ws + ((size_t)20 << 20));     // 8 MB  attn output

  const int M = 4096, N = 1024, K = 1024;

  k_cvt<<<(M * K / 4 + 255) / 256, 256, 0, stream>>>(x,  xb,  M * K / 4);
  k_cvt<<<(N * K / 4 + 255) / 256, 256, 0, stream>>>(Wq, wqb, N * K / 4);
  k_cvt<<<(N * K / 4 + 255) / 256, 256, 0, stream>>>(Wo, wob, N * K / 4);

  k_gemm_bt<true ><<<dim3(8, 32), 256, 0, stream>>>(xb, wqb, bq, qb,    M, N, K);
  k_attn          <<<dim3(16, 32), 256, 0, stream>>>(qb, ab);
  k_gemm_bt<false><<<dim3(8, 32), 256, 0, stream>>>(ab, wob, bo, d_out, M, N, K);
}

// Round 6
// 133.175 us; speedup vs baseline: 1.2131x; 1.0165x over previous
//
#include <hip/hip_runtime.h>
#include <hip/hip_bf16.h>

typedef __bf16 bf16x8 __attribute__((ext_vector_type(8)));
typedef float  f32x4  __attribute__((ext_vector_type(4)));

// async 16B global -> LDS (wave-uniform LDS base + lane*16)
__device__ __forceinline__ void gload_lds16(const void* g, void* l) {
  __builtin_amdgcn_global_load_lds(
      (const __attribute__((address_space(1))) unsigned int*)g,
      (__attribute__((address_space(3))) unsigned int*)l, 16, 0, 0);
}

// ---------------- fp32 -> bf16 convert (vectorized) ----------------
__global__ void k_cvt(const float* __restrict__ s, __bf16* __restrict__ d, int n4) {
  int i = blockIdx.x * blockDim.x + threadIdx.x;
  if (i >= n4) return;
  float4 v = ((const float4*)s)[i];
  union { __bf16 h[4]; uint2 u; } o;
  o.h[0] = (__bf16)v.x; o.h[1] = (__bf16)v.y;
  o.h[2] = (__bf16)v.z; o.h[3] = (__bf16)v.w;
  ((uint2*)d)[i] = o.u;
}

// ---------------- C[M,N] = A[M,K] @ B[N,K]^T + bias ----------------
// 128x64 tile, BK=32, 256 threads (4 waves 2x2). grid = (N/64, M/128) = 512 blocks
// -> 2 blocks/CU (was 1 with 128x128).
template<bool OUT_BF16>
__global__ __launch_bounds__(256, 2)
void k_gemm_bt(const __bf16* __restrict__ A, const __bf16* __restrict__ B,
               const float* __restrict__ bias, void* __restrict__ C,
               int M, int N, int K) {
  __shared__ __align__(16) __bf16 At[128 * 32];
  __shared__ __align__(16) __bf16 Bt[64 * 32];
  const int tid  = threadIdx.x;
  const int lane = tid & 63;
  const int w    = tid >> 6;
  const int wr   = w >> 1, wc = w & 1;
  const int bm   = blockIdx.y * 128, bn = blockIdx.x * 64;

  f32x4 acc[4][2] = {};

  const __bf16* ga = A + (size_t)(bm + (tid >> 2)) * K + (tid & 3) * 8;
  const __bf16* gb = B + (size_t)(bn + (tid >> 2)) * K + (tid & 3) * 8;

  for (int k0 = 0; k0 < K; k0 += 32) {
    __syncthreads();
    gload_lds16(ga + k0,                  &At[(w * 16) * 32]);
    gload_lds16(ga + k0 + (size_t)64 * K, &At[(64 + w * 16) * 32]);
    gload_lds16(gb + k0,                  &Bt[(w * 16) * 32]);
    __syncthreads();

    bf16x8 a[4], b[2];
#pragma unroll
    for (int mt = 0; mt < 4; ++mt)
      a[mt] = *(const bf16x8*)&At[(wr * 64 + mt * 16 + (lane & 15)) * 32 + (lane >> 4) * 8];
#pragma unroll
    for (int nt = 0; nt < 2; ++nt)
      b[nt] = *(const bf16x8*)&Bt[(wc * 32 + nt * 16 + (lane & 15)) * 32 + (lane >> 4) * 8];
    __builtin_amdgcn_s_setprio(1);
#pragma unroll
    for (int mt = 0; mt < 4; ++mt)
#pragma unroll
      for (int nt = 0; nt < 2; ++nt)
        acc[mt][nt] = __builtin_amdgcn_mfma_f32_16x16x32_bf16(a[mt], b[nt], acc[mt][nt], 0, 0, 0);
    __builtin_amdgcn_s_setprio(0);
  }

#pragma unroll
  for (int nt = 0; nt < 2; ++nt) {
    const int col = bn + wc * 32 + nt * 16 + (lane & 15);
    const float bv = bias[col];
#pragma unroll
    for (int mt = 0; mt < 4; ++mt) {
#pragma unroll
      for (int r = 0; r < 4; ++r) {
        const int row = bm + wr * 64 + mt * 16 + (lane >> 4) * 4 + r;
        const float v = acc[mt][nt][r] + bv;
        if (OUT_BF16) ((__bf16*)C)[(size_t)row * N + col] = (__bf16)v;
        else          ((float*)C)[(size_t)row * N + col]  = v;
      }
    }
  }
}

// ---------------- flash attention (Q = K = V = qbuf head slices) ----------------
// 512 threads = 8 waves, each wave owns 16 q-rows (1 qf). grid (16,32) -> 2 blk/CU
// = 16 waves/CU. Kt/Vt layouts + swizzles identical to the round-5 passing kernel;
// Pt padded to stride 72 (write 2-way, read <=4-way). Softmax: base-2 exp folded
// into one FMA per element + defer-rescale (threshold 5.77 in log2 domain).
#define SWZ(row, col)  ((row) * 64 + ((col) ^ (((row) & 7) << 3)))
#define SWZV(row, col) ((row) * 64 + ((col) ^ ((row) & 56)))

__global__ __launch_bounds__(512, 4)
void k_attn(const __bf16* __restrict__ q, __bf16* __restrict__ o) {
  __shared__ __bf16 Kt[64 * 64];
  __shared__ __bf16 Vt[64 * 64];       // transposed: Vt[d][kv], SWZV swizzle
  __shared__ __bf16 Pt[8][16 * 72];    // per-wave P[q][kv], padded stride 72
  const int tid = threadIdx.x, lane = tid & 63, w = tid >> 6;
  const int g = lane >> 4, l15 = lane & 15;
  const int bh = blockIdx.y;
  const size_t base = ((size_t)(bh >> 4) * 2048) * 1024 + (bh & 15) * 64;
  const int q0 = blockIdx.x * 128 + w * 16;

  // Q fragment (B-operand role): row q0+l15, d = 32ks+8g..+7
  bf16x8 qb[2];
#pragma unroll
  for (int ks = 0; ks < 2; ++ks)
    qb[ks] = *(const bf16x8*)&q[base + (size_t)(q0 + l15) * 1024 + ks * 32 + g * 8];

  f32x4 O[4] = {};
  float m2 = -3e38f;                  // running max of c2-scaled scores (log2 dom.)
  float l_run = 0.f;
  const float c2 = 0.18033688f;       // 0.125 * log2(e)

  const int r0 = tid >> 3, c0 = (tid & 7) * 8;   // staging: 512 thr x 8 elems = 64x64

  // prologue: tile 0 into registers
  bf16x8 v0 = *(const bf16x8*)&q[base + (size_t)r0 * 1024 + c0];

  for (int kt = 0; kt < 2048; kt += 64) {
    __syncthreads();                   // previous tile's LDS reads complete
    *(bf16x8*)&Kt[SWZ(r0, c0)] = v0;
#pragma unroll
    for (int j = 0; j < 8; ++j)
      Vt[SWZV(c0 + j, r0)] = v0[j];
    __syncthreads();

    // prefetch next tile into registers
    if (kt < 2048 - 64)
      v0 = *(const bf16x8*)&q[base + (size_t)(kt + 64 + r0) * 1024 + c0];

    // ---- S^T[kv, q] = K · Q^T (raw scores)
    f32x4 s[4] = {};
#pragma unroll
    for (int ks = 0; ks < 2; ++ks) {
#pragma unroll
      for (int kvf = 0; kvf < 4; ++kvf) {
        bf16x8 ka = *(const bf16x8*)&Kt[SWZ(kvf * 16 + l15, ks * 32 + g * 8)];
        s[kvf] = __builtin_amdgcn_mfma_f32_16x16x32_bf16(ka, qb[ks], s[kvf], 0, 0, 0);
      }
    }

    // ---- online softmax (base-2), defer-rescale
    float mx = -3e38f;
#pragma unroll
    for (int kvf = 0; kvf < 4; ++kvf)
#pragma unroll
      for (int r = 0; r < 4; ++r)
        mx = fmaxf(mx, s[kvf][r]);
    mx = fmaxf(mx, __shfl_xor(mx, 16));
    mx = fmaxf(mx, __shfl_xor(mx, 32));
    mx *= c2;
    if (!__all(mx - m2 <= 5.77f)) {
      const float mnew = fmaxf(m2, mx);
      const float ps = exp2f(m2 - mnew);
      m2 = mnew;
      l_run *= ps;
#pragma unroll
      for (int r = 0; r < 4; ++r) {
        const float rs = __shfl(ps, g * 4 + r);
#pragma unroll
        for (int nf = 0; nf < 4; ++nf)
          O[nf][r] *= rs;
      }
    }
    float lsum = 0.f;
#pragma unroll
    for (int kvf = 0; kvf < 4; ++kvf) {
#pragma unroll
      for (int r = 0; r < 4; ++r) {
        const float p = exp2f(fmaf(s[kvf][r], c2, -m2));   // one FMA + one exp2
        s[kvf][r] = p;
        lsum += p;
      }
    }
    lsum += __shfl_xor(lsum, 16);
    lsum += __shfl_xor(lsum, 32);
    l_run += lsum;
    // P[q][kv] into per-wave Pt (4 consecutive kv per lane -> one b64)
#pragma unroll
    for (int kvf = 0; kvf < 4; ++kvf) {
      union { __bf16 h[4]; uint2 u; } pk;
      pk.h[0] = (__bf16)s[kvf][0]; pk.h[1] = (__bf16)s[kvf][1];
      pk.h[2] = (__bf16)s[kvf][2]; pk.h[3] = (__bf16)s[kvf][3];
      *(uint2*)&Pt[w][l15 * 72 + kvf * 16 + g * 4] = pk.u;
    }

    // ---- PV: O[q, d] += P[q, kv] * V[kv, d]
#pragma unroll
    for (int ks = 0; ks < 2; ++ks) {
      bf16x8 pa = *(const bf16x8*)&Pt[w][l15 * 72 + ks * 32 + g * 8];
      __builtin_amdgcn_s_setprio(1);
#pragma unroll
      for (int nf = 0; nf < 4; ++nf) {
        bf16x8 vb = *(const bf16x8*)&Vt[SWZV(nf * 16 + l15, ks * 32 + g * 8)];
        O[nf] = __builtin_amdgcn_mfma_f32_16x16x32_bf16(pa, vb, O[nf], 0, 0, 0);
      }
      __builtin_amdgcn_s_setprio(0);
    }
  }

  // ---- epilogue: O / l
  float inv[4];
#pragma unroll
  for (int r = 0; r < 4; ++r)
    inv[r] = 1.0f / __shfl(l_run, g * 4 + r);
#pragma unroll
  for (int nf = 0; nf < 4; ++nf) {
#pragma unroll
    for (int r = 0; r < 4; ++r) {
      const int row = q0 + g * 4 + r;
      const int col = nf * 16 + l15;
      o[base + (size_t)row * 1024 + col] = (__bf16)(O[nf][r] * inv[r]);
    }
  }
}

// ---------------- launch ----------------
extern "C" void kernel_launch(void* const* d_in, const int* in_sizes, int n_in,
                              void* d_out, int out_size, void* d_ws, size_t ws_size,
                              hipStream_t stream) {
  const float* x  = (const float*)d_in[0];
  const float* Wq = (const float*)d_in[1];
  const float* bq = (const float*)d_in[2];
  const float* Wo = (const float*)d_in[3];
  const float* bo = (const float*)d_in[4];

  char* ws = (char*)d_ws;
  __bf16* xb  = (__bf16*)(ws);                          // 8 MB  [4096,1024]
  __bf16* wqb = (__bf16*)(ws + ((size_t)8  << 20));     // 2 MB  [1024,1024]
  __bf16* wob = (__bf16*)(ws + ((size_t)10 << 20));     // 2 MB
  __bf16* qb  = (__bf16*)(ws + ((size_t)12 << 20));     // 8 MB  q projection
  __bf16* ab  = (__bf16*)(ws + ((size_t)20 << 20));     // 8 MB  attn output

  const int M = 4096, N = 1024, K = 1024;

  k_cvt<<<(M * K / 4 + 255) / 256, 256, 0, stream>>>(x,  xb,  M * K / 4);
  k_cvt<<<(N * K / 4 + 255) / 256, 256, 0, stream>>>(Wq, wqb, N * K / 4);
  k_cvt<<<(N * K / 4 + 255) / 256, 256, 0, stream>>>(Wo, wob, N * K / 4);

  k_gemm_bt<true ><<<dim3(16, 32), 256, 0, stream>>>(xb, wqb, bq, qb,    M, N, K);
  k_attn          <<<dim3(16, 32), 512, 0, stream>>>(qb, ab);
  k_gemm_bt<false><<<dim3(16, 32), 256, 0, stream>>>(ab, wob, bo, d_out, M, N, K);
}

// Round 7
// 125.347 us; speedup vs baseline: 1.2889x; 1.0624x over previous
//
#include <hip/hip_runtime.h>
#include <hip/hip_bf16.h>

typedef __bf16 bf16x8 __attribute__((ext_vector_type(8)));
typedef float  f32x4  __attribute__((ext_vector_type(4)));
typedef float  f32x16 __attribute__((ext_vector_type(16)));

// async 16B global -> LDS (wave-uniform LDS base + lane*16)
__device__ __forceinline__ void gload_lds16(const void* g, void* l) {
  __builtin_amdgcn_global_load_lds(
      (const __attribute__((address_space(1))) unsigned int*)g,
      (__attribute__((address_space(3))) unsigned int*)l, 16, 0, 0);
}

// ---------------- fp32 -> bf16 convert (vectorized) ----------------
__global__ void k_cvt(const float* __restrict__ s, __bf16* __restrict__ d, int n4) {
  int i = blockIdx.x * blockDim.x + threadIdx.x;
  if (i >= n4) return;
  float4 v = ((const float4*)s)[i];
  union { __bf16 h[4]; uint2 u; } o;
  o.h[0] = (__bf16)v.x; o.h[1] = (__bf16)v.y;
  o.h[2] = (__bf16)v.z; o.h[3] = (__bf16)v.w;
  ((uint2*)d)[i] = o.u;
}

// ---------------- C[M,N] = A[M,K] @ B[N,K]^T + bias ----------------
// 128x64 tile, BK=32, 256 threads (4 waves 2x2). grid = (N/64, M/128) = 512 blocks.
// (round-6 proven version, verbatim)
template<bool OUT_BF16>
__global__ __launch_bounds__(256, 2)
void k_gemm_bt(const __bf16* __restrict__ A, const __bf16* __restrict__ B,
               const float* __restrict__ bias, void* __restrict__ C,
               int M, int N, int K) {
  __shared__ __align__(16) __bf16 At[128 * 32];
  __shared__ __align__(16) __bf16 Bt[64 * 32];
  const int tid  = threadIdx.x;
  const int lane = tid & 63;
  const int w    = tid >> 6;
  const int wr   = w >> 1, wc = w & 1;
  const int bm   = blockIdx.y * 128, bn = blockIdx.x * 64;

  f32x4 acc[4][2] = {};

  const __bf16* ga = A + (size_t)(bm + (tid >> 2)) * K + (tid & 3) * 8;
  const __bf16* gb = B + (size_t)(bn + (tid >> 2)) * K + (tid & 3) * 8;

  for (int k0 = 0; k0 < K; k0 += 32) {
    __syncthreads();
    gload_lds16(ga + k0,                  &At[(w * 16) * 32]);
    gload_lds16(ga + k0 + (size_t)64 * K, &At[(64 + w * 16) * 32]);
    gload_lds16(gb + k0,                  &Bt[(w * 16) * 32]);
    __syncthreads();

    bf16x8 a[4], b[2];
#pragma unroll
    for (int mt = 0; mt < 4; ++mt)
      a[mt] = *(const bf16x8*)&At[(wr * 64 + mt * 16 + (lane & 15)) * 32 + (lane >> 4) * 8];
#pragma unroll
    for (int nt = 0; nt < 2; ++nt)
      b[nt] = *(const bf16x8*)&Bt[(wc * 32 + nt * 16 + (lane & 15)) * 32 + (lane >> 4) * 8];
    __builtin_amdgcn_s_setprio(1);
#pragma unroll
    for (int mt = 0; mt < 4; ++mt)
#pragma unroll
      for (int nt = 0; nt < 2; ++nt)
        acc[mt][nt] = __builtin_amdgcn_mfma_f32_16x16x32_bf16(a[mt], b[nt], acc[mt][nt], 0, 0, 0);
    __builtin_amdgcn_s_setprio(0);
  }

#pragma unroll
  for (int nt = 0; nt < 2; ++nt) {
    const int col = bn + wc * 32 + nt * 16 + (lane & 15);
    const float bv = bias[col];
#pragma unroll
    for (int mt = 0; mt < 4; ++mt) {
#pragma unroll
      for (int r = 0; r < 4; ++r) {
        const int row = bm + wr * 64 + mt * 16 + (lane >> 4) * 4 + r;
        const float v = acc[mt][nt][r] + bv;
        if (OUT_BF16) ((__bf16*)C)[(size_t)row * N + col] = (__bf16)v;
        else          ((float*)C)[(size_t)row * N + col]  = v;
      }
    }
  }
}

// ---------------- flash attention (Q = K = V), 32x32x16 MFMA ----------------
// 256 threads = 4 waves x 32 q-rows. grid (16, 32) -> 2 blocks/CU.
// Kt[kv][d], Vt[d][kv] both under one swizzle: col ^= ((row&7)^(row>>3))<<3.
// Verified conflict-free: Kt b128 writes, Vt scalar transpose writes,
// A-frag reads (row=32kvf+l31), B-frag reads (row=32dh+l31).
// S^T = mfma(A=K, B=Q): lane holds q=lane&31, kv=(reg&3)+8*(reg>>2)+4h.
// P->PV A-frag needs only a lane^32 word exchange (8 shfl_xor), no LDS.
#define SWZ2(row, col) ((row) * 64 + ((col) ^ (((((row) & 7) ^ ((row) >> 3)) & 7) << 3)))

__global__ __launch_bounds__(256, 2)
void k_attn(const __bf16* __restrict__ q, __bf16* __restrict__ o) {
  __shared__ __align__(16) __bf16 Kt[64 * 64];
  __shared__ __align__(16) __bf16 Vt[64 * 64];
  const int tid = threadIdx.x, lane = tid & 63, w = tid >> 6;
  const int l31 = lane & 31, h = lane >> 5;
  const int bh = blockIdx.y;
  const size_t base = ((size_t)(bh >> 4) * 2048) * 1024 + (bh & 15) * 64;
  const int q0 = blockIdx.x * 128 + w * 32;

  // Q B-frags: col q = q0+l31, k(d) = 16ks + 8h + 0..7
  bf16x8 qb[4];
#pragma unroll
  for (int ks = 0; ks < 4; ++ks)
    qb[ks] = *(const bf16x8*)&q[base + (size_t)(q0 + l31) * 1024 + ks * 16 + h * 8];

  f32x16 O[2] = {};                 // dh = 0,1 ; row q=(reg&3)+8*(reg>>2)+4h, col d=32dh+l31
  float m2 = -3e38f, l_run = 0.f;
  const float c2 = 0.18033688f;     // 0.125 * log2(e)

  const int r0 = tid >> 3, c0 = (tid & 7) * 8;   // staging coords (32 rows x 64 cols per load)

  // prologue: tile 0 into registers
  bf16x8 v0 = *(const bf16x8*)&q[base + (size_t)r0 * 1024 + c0];
  bf16x8 v1 = *(const bf16x8*)&q[base + (size_t)(32 + r0) * 1024 + c0];

  for (int kt = 0; kt < 2048; kt += 64) {
    __syncthreads();                               // prior tile's LDS reads complete
    *(bf16x8*)&Kt[SWZ2(r0, c0)]      = v0;
    *(bf16x8*)&Kt[SWZ2(r0 + 32, c0)] = v1;
#pragma unroll
    for (int j = 0; j < 8; ++j) {
      Vt[SWZ2(c0 + j, r0)]      = v0[j];
      Vt[SWZ2(c0 + j, r0 + 32)] = v1[j];
    }
    __syncthreads();                               // tiles visible

    // prefetch next tile into registers (consumed at next iteration's writes)
    if (kt < 2048 - 64) {
      v0 = *(const bf16x8*)&q[base + (size_t)(kt + 64 + r0) * 1024 + c0];
      v1 = *(const bf16x8*)&q[base + (size_t)(kt + 96 + r0) * 1024 + c0];
    }

    // ---- QK^T: S^T[kv, q], 64kv x 32q per wave, 8 mfma
    f32x16 s[2] = {};
#pragma unroll
    for (int kvf = 0; kvf < 2; ++kvf) {
#pragma unroll
      for (int ks = 0; ks < 4; ++ks) {
        bf16x8 ka = *(const bf16x8*)&Kt[SWZ2(kvf * 32 + l31, ks * 16 + h * 8)];
        s[kvf] = __builtin_amdgcn_mfma_f32_32x32x16_bf16(ka, qb[ks], s[kvf], 0, 0, 0);
      }
    }

    // ---- online softmax (base-2, defer-rescale). lane's q = l31; kv spread over regs+h.
    float mx = -3e38f;
#pragma unroll
    for (int kvf = 0; kvf < 2; ++kvf)
#pragma unroll
      for (int r = 0; r < 16; ++r)
        mx = fmaxf(mx, s[kvf][r]);
    mx = fmaxf(mx, __shfl_xor(mx, 32));
    mx *= c2;
    if (!__all(mx - m2 <= 5.77f)) {
      const float mnew = fmaxf(m2, mx);
      const float ps = exp2f(m2 - mnew);
      m2 = mnew;
      l_run *= ps;
#pragma unroll
      for (int r = 0; r < 16; ++r) {
        const int qrow = (r & 3) + 8 * (r >> 2) + 4 * h;
        const float rs = __shfl(ps, qrow);
        O[0][r] *= rs;
        O[1][r] *= rs;
      }
    }
    // P = exp2(s*c2 - m2), packed to bf16 pairs: word(kvf,rq,t) = kv pair
    // base 32kvf + 8rq + 4h + 2t  (regs 4rq+2t, 4rq+2t+1)
    float lsum = 0.f;
    unsigned P[2][4][2];
#pragma unroll
    for (int kvf = 0; kvf < 2; ++kvf) {
#pragma unroll
      for (int rq = 0; rq < 4; ++rq) {
#pragma unroll
        for (int t = 0; t < 2; ++t) {
          const float p0 = exp2f(fmaf(s[kvf][rq * 4 + t * 2],     c2, -m2));
          const float p1 = exp2f(fmaf(s[kvf][rq * 4 + t * 2 + 1], c2, -m2));
          lsum += p0 + p1;
          union { __bf16 b[2]; unsigned u; } pk;
          pk.b[0] = (__bf16)p0; pk.b[1] = (__bf16)p1;
          P[kvf][rq][t] = pk.u;
        }
      }
    }
    lsum += __shfl_xor(lsum, 32);
    l_run += lsum;

    // lane^32 exchange: lane h sends its rq = 2k+(1-h) words, receives partner's
    // rq = 2k+h words. R[kvf][k][t] == partner's P at rq = 2k + h(this lane).
    unsigned R[2][2][2];
#pragma unroll
    for (int kvf = 0; kvf < 2; ++kvf)
#pragma unroll
      for (int k = 0; k < 2; ++k)
#pragma unroll
        for (int t = 0; t < 2; ++t)
          R[kvf][k][t] = (unsigned)__shfl_xor(
              (int)(h ? P[kvf][2 * k][t] : P[kvf][2 * k + 1][t]), 32);

    // ---- PV: O[q,d] += P[q,kv] V[kv,d]; pa[ko] covers kv = 16ko + 8h + 0..7
#pragma unroll
    for (int dh = 0; dh < 2; ++dh) {
#pragma unroll
      for (int ko = 0; ko < 4; ++ko) {
        const int kvf = ko >> 1, k2 = (ko & 1) * 2, kk = ko & 1;
        union { unsigned u[4]; bf16x8 v; } pu;
        pu.u[0] = h ? R[kvf][kk][0]     : P[kvf][k2][0];
        pu.u[1] = h ? R[kvf][kk][1]     : P[kvf][k2][1];
        pu.u[2] = h ? P[kvf][k2 + 1][0] : R[kvf][kk][0];
        pu.u[3] = h ? P[kvf][k2 + 1][1] : R[kvf][kk][1];
        bf16x8 vb = *(const bf16x8*)&Vt[SWZ2(dh * 32 + l31, ko * 16 + h * 8)];
        O[dh] = __builtin_amdgcn_mfma_f32_32x32x16_bf16(pu.v, vb, O[dh], 0, 0, 0);
      }
    }
  }

  // ---- epilogue: O / l  (l lives at lane q; route per output row)
  const float linv = 1.0f / l_run;
#pragma unroll
  for (int r = 0; r < 16; ++r) {
    const int qrow = (r & 3) + 8 * (r >> 2) + 4 * h;
    const float rs = __shfl(linv, qrow);
    o[base + (size_t)(q0 + qrow) * 1024 + l31]      = (__bf16)(O[0][r] * rs);
    o[base + (size_t)(q0 + qrow) * 1024 + 32 + l31] = (__bf16)(O[1][r] * rs);
  }
}

// ---------------- launch ----------------
extern "C" void kernel_launch(void* const* d_in, const int* in_sizes, int n_in,
                              void* d_out, int out_size, void* d_ws, size_t ws_size,
                              hipStream_t stream) {
  const float* x  = (const float*)d_in[0];
  const float* Wq = (const float*)d_in[1];
  const float* bq = (const float*)d_in[2];
  const float* Wo = (const float*)d_in[3];
  const float* bo = (const float*)d_in[4];

  char* ws = (char*)d_ws;
  __bf16* xb  = (__bf16*)(ws);                          // 8 MB  [4096,1024]
  __bf16* wqb = (__bf16*)(ws + ((size_t)8  << 20));     // 2 MB
  __bf16* wob = (__bf16*)(ws + ((size_t)10 << 20));     // 2 MB
  __bf16* qb  = (__bf16*)(ws + ((size_t)12 << 20));     // 8 MB  q projection
  __bf16* ab  = (__bf16*)(ws + ((size_t)20 << 20));     // 8 MB  attn output

  const int M = 4096, N = 1024, K = 1024;

  k_cvt<<<(M * K / 4 + 255) / 256, 256, 0, stream>>>(x,  xb,  M * K / 4);
  k_cvt<<<(N * K / 4 + 255) / 256, 256, 0, stream>>>(Wq, wqb, N * K / 4);
  k_cvt<<<(N * K / 4 + 255) / 256, 256, 0, stream>>>(Wo, wob, N * K / 4);

  k_gemm_bt<true ><<<dim3(16, 32), 256, 0, stream>>>(xb, wqb, bq, qb,    M, N, K);
  k_attn          <<<dim3(16, 32), 256, 0, stream>>>(qb, ab);
  k_gemm_bt<false><<<dim3(16, 32), 256, 0, stream>>>(ab, wob, bo, d_out, M, N, K);
}